// Round 13
// baseline (216.101 us; speedup 1.0000x reference)
//
#include <hip/hip_runtime.h>
#include <cmath>
#include <cfloat>

namespace {

constexpr int kB   = 1024;
constexpr int kL   = 64;
constexpr int kHid = 512;
constexpr int kLow = 20;
constexpr int kLM1 = 63;              // L-1
constexpr int kRowElems = kL * kLow;  // 1280 floats per batch row of h0/c0

typedef float v2f __attribute__((ext_vector_type(2)));

__device__ __forceinline__ float fsig(float x) {
  return __builtin_amdgcn_rcpf(1.0f + __expf(-x));
}
__device__ __forceinline__ float ftanhf(float x) {
  return 1.0f - 2.0f * __builtin_amdgcn_rcpf(1.0f + __expf(2.0f * x));
}
__device__ __forceinline__ int rdl_i(int v, int l) {
  return __builtin_amdgcn_readlane(v, l);
}
__device__ __forceinline__ float rdl_f(float v, int l) {
  return __int_as_float(__builtin_amdgcn_readlane(__float_as_int(v), l));
}

// DPP helpers (ctrl must be a literal -> macros).
#define DPPI(v, ctrl) __builtin_amdgcn_update_dpp((v), (v), (ctrl), 0xF, 0xF, false)
#define DPPF(v, ctrl) __int_as_float(DPPI(__float_as_int(v), (ctrl)))
#define DPPF0(v, ctrl)                                                        \
  __int_as_float(__builtin_amdgcn_update_dpp(0, __float_as_int(v), (ctrl),    \
                                             0xF, 0xF, true))
#define UMAX_STAGE(CTRL)                                                      \
  {                                                                           \
    const unsigned o_ = (unsigned)DPPI((int)m, CTRL);                         \
    m = (m > o_) ? m : o_;                                                    \
  }

// packed 2xf32 FMA
#define PKFMA(ACC, X, W)                                                      \
  asm("v_pk_fma_f32 %0, %1, %2, %0" : "+v"(ACC) : "v"(X), "v"(W))

// logit: sum over each 32-lane half; totals land in lanes 31 and 63.
#define LOGIT_REDUCE(PR_)                                                     \
  {                                                                           \
    PR_ += DPPF0(PR_, 0xB1);                                                  \
    PR_ += DPPF0(PR_, 0x4E);                                                  \
    PR_ += DPPF0(PR_, 0x141);                                                 \
    PR_ += DPPF0(PR_, 0x140);                                                 \
    PR_ += DPPF0(PR_, 0x142);                                                 \
  }

// ---------------------------------------------------------------------------
// Phase 1 (unchanged, known-best): h0/c0 = X @ W_reduce + b
// ---------------------------------------------------------------------------
__global__ __launch_bounds__(256, 6)
void reduce_kernel(const float* __restrict__ Xh, const float* __restrict__ Xc,
                   const float* __restrict__ W, const float* __restrict__ bv,
                   float* __restrict__ H0, float* __restrict__ C0) {
  __shared__ float xs[5184];       // 64 rows x pitch 65; reused as scratch
  __shared__ float wsm[64 * 20];   // W chunk

  const int bid = blockIdx.x;
  const float* __restrict__ X = (bid < kB) ? Xh : Xc;
  float* __restrict__ O       = (bid < kB) ? H0 : C0;
  const int b = bid & (kB - 1);
  X += (size_t)b * kL * kHid;
  O += (size_t)b * kRowElems;

  const int tid  = threadIdx.x;
  const int wave = tid >> 6;
  const int lane = tid & 63;

  float acc[20];
#pragma unroll
  for (int d = 0; d < 20; ++d) acc[d] = 0.0f;

  for (int ch = 0; ch < 8; ++ch) {
    __syncthreads();
#pragma unroll
    for (int r = 0; r < 4; ++r) {
      int f   = r * 256 + tid;
      int row = f >> 4;
      int c4  = (f & 15) << 2;
      float4 v = *(const float4*)(X + row * kHid + ch * 64 + c4);
      *(float4*)(xs + row * 65 + c4) = v;
    }
#pragma unroll
    for (int r = 0; r < 5; ++r) {
      int f = r * 256 + tid;
      wsm[f] = W[ch * 1280 + f];
    }
    __syncthreads();
#pragma unroll
    for (int kk = 0; kk < 16; ++kk) {
      int k = wave * 16 + kk;
      float x = xs[lane * 65 + k];
      const float4* wp = (const float4*)(wsm + k * 20);
      float4 w0 = wp[0], w1 = wp[1], w2 = wp[2], w3 = wp[3], w4 = wp[4];
      acc[0]  = fmaf(x, w0.x, acc[0]);  acc[1]  = fmaf(x, w0.y, acc[1]);
      acc[2]  = fmaf(x, w0.z, acc[2]);  acc[3]  = fmaf(x, w0.w, acc[3]);
      acc[4]  = fmaf(x, w1.x, acc[4]);  acc[5]  = fmaf(x, w1.y, acc[5]);
      acc[6]  = fmaf(x, w1.z, acc[6]);  acc[7]  = fmaf(x, w1.w, acc[7]);
      acc[8]  = fmaf(x, w2.x, acc[8]);  acc[9]  = fmaf(x, w2.y, acc[9]);
      acc[10] = fmaf(x, w2.z, acc[10]); acc[11] = fmaf(x, w2.w, acc[11]);
      acc[12] = fmaf(x, w3.x, acc[12]); acc[13] = fmaf(x, w3.y, acc[13]);
      acc[14] = fmaf(x, w3.z, acc[14]); acc[15] = fmaf(x, w3.w, acc[15]);
      acc[16] = fmaf(x, w4.x, acc[16]); acc[17] = fmaf(x, w4.y, acc[17]);
      acc[18] = fmaf(x, w4.z, acc[18]); acc[19] = fmaf(x, w4.w, acc[19]);
    }
  }

  __syncthreads();
  float* red = xs;
#pragma unroll
  for (int d = 0; d < 20; ++d) red[wave * 1280 + lane * 20 + d] = acc[d];
  __syncthreads();
#pragma unroll
  for (int r = 0; r < 5; ++r) {
    int f = r * 256 + tid;
    float s = (red[f] + red[1280 + f]) + (red[2560 + f] + red[3840 + f]);
    O[f] = s + bv[f % 20];
  }
}

// Init eval of one (pair,dim) unit for BOTH rows, sharing the 50 Wt reads.
#define EVAL_UNIT2(PP_, DD_)                                                  \
  {                                                                           \
    float aiA = bcs[DD_], afA = bcs[20 + DD_], agA = bcs[40 + DD_],           \
          auA = bcs[60 + DD_], aoA = bcs[80 + DD_];                           \
    float aiB = aiA, afB = afA, agB = agA, auB = auA, aoB = aoA;              \
    const int xa_ = (PP_)*20, xb_ = (PP_ + 1)*20, wr_ = (DD_)*44;             \
    _Pragma("unroll")                                                         \
    for (int kq = 0; kq < 10; ++kq) {                                         \
      const float4 xqA = (kq < 5)                                             \
          ? *(const float4*)(h_sA + xa_ + kq * 4)                             \
          : *(const float4*)(h_sA + xb_ + (kq - 5) * 4);                      \
      const float4 xqB = (kq < 5)                                             \
          ? *(const float4*)(h_sB + xa_ + kq * 4)                             \
          : *(const float4*)(h_sB + xb_ + (kq - 5) * 4);                      \
      const float4 wi = *(const float4*)(Wt + wr_ + kq * 4);                  \
      const float4 wf = *(const float4*)(Wt + 880  + wr_ + kq * 4);           \
      const float4 wg = *(const float4*)(Wt + 1760 + wr_ + kq * 4);           \
      const float4 wu = *(const float4*)(Wt + 2640 + wr_ + kq * 4);           \
      const float4 wo = *(const float4*)(Wt + 3520 + wr_ + kq * 4);           \
      aiA = fmaf(xqA.x, wi.x, aiA); aiA = fmaf(xqA.y, wi.y, aiA);             \
      aiA = fmaf(xqA.z, wi.z, aiA); aiA = fmaf(xqA.w, wi.w, aiA);             \
      afA = fmaf(xqA.x, wf.x, afA); afA = fmaf(xqA.y, wf.y, afA);             \
      afA = fmaf(xqA.z, wf.z, afA); afA = fmaf(xqA.w, wf.w, afA);             \
      agA = fmaf(xqA.x, wg.x, agA); agA = fmaf(xqA.y, wg.y, agA);             \
      agA = fmaf(xqA.z, wg.z, agA); agA = fmaf(xqA.w, wg.w, agA);             \
      auA = fmaf(xqA.x, wu.x, auA); auA = fmaf(xqA.y, wu.y, auA);             \
      auA = fmaf(xqA.z, wu.z, auA); auA = fmaf(xqA.w, wu.w, auA);             \
      aoA = fmaf(xqA.x, wo.x, aoA); aoA = fmaf(xqA.y, wo.y, aoA);             \
      aoA = fmaf(xqA.z, wo.z, aoA); aoA = fmaf(xqA.w, wo.w, aoA);             \
      aiB = fmaf(xqB.x, wi.x, aiB); aiB = fmaf(xqB.y, wi.y, aiB);             \
      aiB = fmaf(xqB.z, wi.z, aiB); aiB = fmaf(xqB.w, wi.w, aiB);             \
      afB = fmaf(xqB.x, wf.x, afB); afB = fmaf(xqB.y, wf.y, afB);             \
      afB = fmaf(xqB.z, wf.z, afB); afB = fmaf(xqB.w, wf.w, afB);             \
      agB = fmaf(xqB.x, wg.x, agB); agB = fmaf(xqB.y, wg.y, agB);             \
      agB = fmaf(xqB.z, wg.z, agB); agB = fmaf(xqB.w, wg.w, agB);             \
      auB = fmaf(xqB.x, wu.x, auB); auB = fmaf(xqB.y, wu.y, auB);             \
      auB = fmaf(xqB.z, wu.z, auB); auB = fmaf(xqB.w, wu.w, auB);             \
      aoB = fmaf(xqB.x, wo.x, aoB); aoB = fmaf(xqB.y, wo.y, aoB);             \
      aoB = fmaf(xqB.z, wo.z, aoB); aoB = fmaf(xqB.w, wo.w, aoB);             \
    }                                                                         \
    {                                                                         \
      const float clA = c_sA[(PP_)*20 + (DD_)],                               \
                  crA = c_sA[(PP_+1)*20 + (DD_)];                             \
      const float cnA = clA * fsig(afA + 1.0f) + crA * fsig(agA + 1.0f) +     \
                        ftanhf(auA) * fsig(aiA);                              \
      const float hnA = fsig(aoA) * ftanhf(cnA);                              \
      nhA[(PP_)*20 + (DD_)] = hnA;  ncA[(PP_)*20 + (DD_)] = cnA;              \
      const float clB = c_sB[(PP_)*20 + (DD_)],                               \
                  crB = c_sB[(PP_+1)*20 + (DD_)];                             \
      const float cnB = clB * fsig(afB + 1.0f) + crB * fsig(agB + 1.0f) +     \
                        ftanhf(auB) * fsig(aiB);                              \
      const float hnB = fsig(aoB) * ftanhf(cnB);                              \
      nhB[(PP_)*20 + (DD_)] = hnB;  ncB[(PP_)*20 + (DD_)] = cnB;              \
    }                                                                         \
  }

// Argmax over z = lgt + g via u32 sort-key + DPP; k=0 when no lane valid.
#define ROW_ARGMAX(LGT_, G_, LEN_, KOUT_)                                     \
  {                                                                           \
    const float zf = (LGT_) + (G_);                                           \
    const unsigned ub = __float_as_uint(zf);                                  \
    unsigned key = ((int)ub < 0) ? ~ub : (ub | 0x80000000u);                  \
    const bool valid = (lane <= n - 2) && ((i + 1 + lane) < (LEN_));          \
    if (!valid) key = 0u;                                                     \
    unsigned m = key;                                                         \
    UMAX_STAGE(0xB1); UMAX_STAGE(0x4E); UMAX_STAGE(0x141);                    \
    UMAX_STAGE(0x140); UMAX_STAGE(0x142); UMAX_STAGE(0x143);                  \
    const unsigned gmax = (unsigned)rdl_i((int)m, 63);                        \
    const unsigned long long bal = __ballot(valid && (key == gmax));          \
    (KOUT_) = bal ? (int)(__ffsll(bal) - 1) : 0;                              \
  }

// Hoist all LDS reads the eval needs (pre-merge values; single-wave in-order).
#define ROW_HOIST(HS, CS, NH, NC, IL_, IR_, PSK_, XL, XT, XR, CL_, CT_, CR_)  \
  {                                                                           \
    _Pragma("unroll")                                                         \
    for (int q = 0; q < 5; ++q) {                                             \
      const float4 tL = *(const float4*)((HS) + (IL_)*20 + q * 4);            \
      const float4 tT = *(const float4*)((NH) + (PSK_)*20 + q * 4);           \
      const float4 tR = *(const float4*)((HS) + (IR_)*20 + q * 4);            \
      XL[2*q] = (v2f){tL.x, tL.y}; XL[2*q+1] = (v2f){tL.z, tL.w};             \
      XT[2*q] = (v2f){tT.x, tT.y}; XT[2*q+1] = (v2f){tT.z, tT.w};             \
      XR[2*q] = (v2f){tR.x, tR.y}; XR[2*q+1] = (v2f){tR.z, tR.w};             \
    }                                                                         \
    CL_ = (CS)[(IL_)*20 + ddc];                                               \
    CT_ = (NC)[(PSK_)*20 + ddc];                                              \
    CR_ = (CS)[(IR_)*20 + ddc];                                               \
  }

#define ROW_MERGE(HS, CS, NH, NC, TGT_, PSK_, ACT_)                           \
  if ((ACT_) && lane < 20) {                                                  \
    (HS)[(TGT_)*20 + lane] = (NH)[(PSK_)*20 + lane];                          \
    (CS)[(TGT_)*20 + lane] = (NC)[(PSK_)*20 + lane];                          \
  }

#define ROW_SHIFT(IDX_, PIDX_, LGT_, K_, ACT_)                                \
  {                                                                           \
    int   sI = DPPI(IDX_,  0x101);                                            \
    int   sP = DPPI(PIDX_, 0x101);                                            \
    float sL = DPPF(LGT_,  0x101);                                            \
    const int   b16i = rdl_i(IDX_, 16),  b32i = rdl_i(IDX_, 32),              \
                b48i = rdl_i(IDX_, 48);                                       \
    const int   b16p = rdl_i(PIDX_, 16), b32p = rdl_i(PIDX_, 32),             \
                b48p = rdl_i(PIDX_, 48);                                      \
    const float b16l = rdl_f(LGT_, 16),  b32l = rdl_f(LGT_, 32),              \
                b48l = rdl_f(LGT_, 48);                                       \
    if (lane == 15) { sI = b16i; sP = b16p; sL = b16l; }                      \
    if (lane == 31) { sI = b32i; sP = b32p; sL = b32l; }                      \
    if (lane == 47) { sI = b48i; sP = b48p; sL = b48l; }                      \
    const bool doI = (ACT_) && (lane >= (K_) + 1) && (lane <= n - 2);         \
    const bool doP = (ACT_) && (lane >= (K_) + 1) && (lane <= n - 3);         \
    if (doI) IDX_ = sI;                                                       \
    if (doP) { PIDX_ = sP; LGT_ = sL; }                                       \
  }

// FMA block for both candidate pairs + gate sums to LDS scratch.
#define ROW_FMASC(XL, XT, XR, SC)                                             \
  {                                                                           \
    v2f a0 = (v2f){0.f, 0.f}, a1 = a0, b0 = a0, b1 = a0;                      \
    _Pragma("unroll")                                                         \
    for (int k2 = 0; k2 < 10; ++k2) {                                         \
      PKFMA(a0, XL[k2], Wv0[k2]);                                             \
      PKFMA(a1, XL[k2], Wv1[k2]);                                             \
      PKFMA(b0, XT[k2], Wv0[k2]);                                             \
      PKFMA(b1, XT[k2], Wv1[k2]);                                             \
    }                                                                         \
    _Pragma("unroll")                                                         \
    for (int k2 = 10; k2 < 20; ++k2) {                                        \
      PKFMA(a0, XT[k2 - 10], Wv0[k2]);                                        \
      PKFMA(a1, XT[k2 - 10], Wv1[k2]);                                        \
      PKFMA(b0, XR[k2 - 10], Wv0[k2]);                                        \
      PKFMA(b1, XR[k2 - 10], Wv1[k2]);                                        \
    }                                                                         \
    if (cact) {                                                               \
      *(v2f*)((SC) + c0)       = (v2f){a0[0]+a0[1]+bb0, a1[0]+a1[1]+bb1};     \
      *(v2f*)((SC) + 100 + c0) = (v2f){b0[0]+b0[1]+bb0, b1[0]+b1[1]+bb1};     \
    }                                                                         \
  }

// Nonlinearities + nh/nc writes + logit reduce + lgt updates (writes guarded).
#define ROW_NONLIN(SC, CL_, CT_, CR_, NH, NC, PL_, PSK_, K_, EV_, LGT_)       \
  {                                                                           \
    const bool hasL = (K_) >= 1, hasR = (K_) <= n - 3;                        \
    const float* scp = (SC) + p * 100;                                        \
    const float gi = scp[ddc], gfl = scp[20 + ddc], gfr = scp[40 + ddc],      \
                gu = scp[60 + ddc], go = scp[80 + ddc];                       \
    const float cl_ = (p == 0) ? (CL_) : (CT_);                               \
    const float cr_ = (p == 0) ? (CT_) : (CR_);                               \
    const float cn_ = cl_ * fsig(gfl + 1.0f) + cr_ * fsig(gfr + 1.0f) +       \
                      ftanhf(gu) * fsig(gi);                                  \
    const float hn_ = fsig(go) * ftanhf(cn_);                                 \
    const int   slot = (p == 0) ? (PL_) : (PSK_);                             \
    const bool  mine = (EV_) && ((p == 0) ? hasL : hasR);                     \
    if (mine && dd < 20) { (NH)[slot*20 + dd] = hn_; (NC)[slot*20 + dd] = cn_; } \
    float pr = (dd < 20) ? hn_ * qv_r : 0.0f;                                 \
    LOGIT_REDUCE(pr);                                                         \
    const float vL = rdl_f(pr, 31);                                           \
    const float vR = rdl_f(pr, 63);                                           \
    if ((EV_) && hasL && lane == (K_) - 1) (LGT_) = vL;                       \
    if ((EV_) && hasR && lane == (K_))     (LGT_) = vR;                       \
  }

// ---------------------------------------------------------------------------
// Phase 2: DUAL-ROW pyramid — one wave processes TWO independent batch rows,
// phases interleaved so each row's stall bubbles are filled by the other
// row's instructions. 60.3 KB LDS -> 2 blocks/CU, 512 blocks all resident.
// ---------------------------------------------------------------------------
__global__ __launch_bounds__(64, 1)
void pyramid_kernel(const float* __restrict__ H0, const float* __restrict__ C0,
                    const float* __restrict__ Wc, const float* __restrict__ bcg,
                    const float* __restrict__ query, const float* __restrict__ U,
                    const int* __restrict__ length, float* __restrict__ out) {
  __shared__ float h_sA[64 * 20], c_sA[64 * 20], nhA[63 * 20], ncA[63 * 20];
  __shared__ float h_sB[64 * 20], c_sB[64 * 20], nhB[63 * 20], ncB[63 * 20];
  __shared__ float Wt[100 * 44];    // transposed W_comp (init only; shared)
  __shared__ float bcs[100];
  __shared__ float qvs[20];
  __shared__ float scA[200], scB[200];

  const int bblk = blockIdx.x;
  const int rowA = 2 * bblk, rowB = 2 * bblk + 1;
  const int lane = threadIdx.x;
  const int p    = lane >> 5;
  const int dd   = lane & 31;
  const int ddc  = dd < 20 ? dd : 19;
  int lenA = length[rowA];
  lenA = lenA < 1 ? 1 : (lenA > 64 ? 64 : lenA);
  int lenB = length[rowB];
  lenB = lenB < 1 ? 1 : (lenB > 64 ? 64 : lenB);

  // ---- stage both rows ----
  {
    const float4* h4A = (const float4*)(H0 + (size_t)rowA * kRowElems);
    const float4* c4A = (const float4*)(C0 + (size_t)rowA * kRowElems);
    const float4* h4B = (const float4*)(H0 + (size_t)rowB * kRowElems);
    const float4* c4B = (const float4*)(C0 + (size_t)rowB * kRowElems);
#pragma unroll
    for (int r = 0; r < 5; ++r) {
      int f = r * 64 + lane;  // 320 float4 per array
      ((float4*)h_sA)[f] = h4A[f];
      ((float4*)c_sA)[f] = c4A[f];
      ((float4*)h_sB)[f] = h4B[f];
      ((float4*)c_sB)[f] = c4B[f];
    }
  }
  for (int f = lane; f < 4000; f += 64) {
    int c = f / 40, k = f - c * 40;
    Wt[c * 44 + k] = Wc[k * 100 + c];
  }
  for (int f = lane; f < 100; f += 64) bcs[f] = bcg[f];
  if (lane < 20) qvs[lane] = query[lane];

  // ---- loop weights: output-column split (shared across both rows) ----
  const bool cact = lane < 50;
  const int  c0   = cact ? 2 * lane : 0;
  const int  c1   = c0 + 1;
  v2f Wv0[20], Wv1[20];
#pragma unroll
  for (int k2 = 0; k2 < 20; ++k2) {
    Wv0[k2] = (v2f){Wc[(2 * k2) * 100 + c0], Wc[(2 * k2 + 1) * 100 + c0]};
    Wv1[k2] = (v2f){Wc[(2 * k2) * 100 + c1], Wc[(2 * k2 + 1) * 100 + c1]};
  }
  const float bb0 = bcg[c0], bb1 = bcg[c1];
  const float qv_r = query[ddc];

  // per-row register bookkeeping
  int   idxA = lane, pidxA = lane;
  int   idxB = lane, pidxB = lane;
  float lgtA = -FLT_MAX, lgtB = -FLT_MAX;

  const int col = lane < 62 ? lane : 62;
  const float u0A = U[rowA * kLM1 + col];
  const float u0B = U[rowB * kLM1 + col];
  float u_cA = U[(size_t)1 * (kB * kLM1) + rowA * kLM1 + col];
  float u_cB = U[(size_t)1 * (kB * kLM1) + rowB * kLM1 + col];

  // ---- init: all 63 adjacent pairs for BOTH rows (shared Wt reads) ----
#pragma unroll 1
  for (int r = 0; r < 20; ++r) {
    int uu = r * 64 + lane;
    if (uu < 1260) {
      int pp = uu / 20, d2 = uu - pp * 20;
      EVAL_UNIT2(pp, d2);
    }
  }
  if (lane < 63) {
    float sA = 0.0f, sB = 0.0f;
#pragma unroll
    for (int q = 0; q < 5; ++q) {
      const float4 qv = *(const float4*)(qvs + q * 4);
      const float4 tA = *(const float4*)(nhA + lane * 20 + q * 4);
      const float4 tB = *(const float4*)(nhB + lane * 20 + q * 4);
      sA = fmaf(tA.x, qv.x, sA); sA = fmaf(tA.y, qv.y, sA);
      sA = fmaf(tA.z, qv.z, sA); sA = fmaf(tA.w, qv.w, sA);
      sB = fmaf(tB.x, qv.x, sB); sB = fmaf(tB.y, qv.y, sB);
      sB = fmaf(tB.z, qv.z, sB); sB = fmaf(tB.w, qv.w, sB);
    }
    lgtA = sA;
    lgtB = sB;
  }

  float gA = -__logf(-__logf(u0A + 1e-20f) + 1e-20f);
  float gB = -__logf(-__logf(u0B + 1e-20f) + 1e-20f);

  const int maxIter = (lenA > lenB ? lenA : lenB) - 1;
#pragma unroll 1
  for (int i = 0; i < maxIter; ++i) {
    const int n = kL - i;
    const bool actA = i < lenA - 1, actB = i < lenB - 1;
    const bool evA  = i < lenA - 2, evB  = i < lenB - 2;

    // ---- argmax both rows (independent DPP chains interleave) ----
    int kA, kB2;
    ROW_ARGMAX(lgtA, gA, lenA, kA);
    ROW_ARGMAX(lgtB, gB, lenB, kB2);

    // ---- U prefetch both rows (2-deep) ----
    float u_dA = 0.0f, u_dB = 0.0f;
    if (i + 2 < kLM1) {
      u_dA = U[(size_t)(i + 2) * (kB * kLM1) + rowA * kLM1 + col];
      u_dB = U[(size_t)(i + 2) * (kB * kLM1) + rowB * kLM1 + col];
    }

    // ---- readlane lookups ----
    const int A_km1 = kA >= 1 ? kA - 1 : 0;
    const int A_kp2 = kA <= n - 3 ? kA + 2 : 0;
    const int A_tgt = rdl_i(idxA, kA),   A_psk = rdl_i(pidxA, kA);
    const int A_iL  = rdl_i(idxA, A_km1), A_pL = rdl_i(pidxA, A_km1);
    const int A_iR  = rdl_i(idxA, A_kp2);
    const int B_km1 = kB2 >= 1 ? kB2 - 1 : 0;
    const int B_kp2 = kB2 <= n - 3 ? kB2 + 2 : 0;
    const int B_tgt = rdl_i(idxB, kB2),   B_psk = rdl_i(pidxB, kB2);
    const int B_iL  = rdl_i(idxB, B_km1), B_pL = rdl_i(pidxB, B_km1);
    const int B_iR  = rdl_i(idxB, B_kp2);

    // ---- row A: hoist reads -> merge -> shift -> FMA+sc ----
    {
      v2f A_xL[10], A_xT[10], A_xR[10];
      float A_cL, A_cT, A_cR;
      ROW_HOIST(h_sA, c_sA, nhA, ncA, A_iL, A_iR, A_psk,
                A_xL, A_xT, A_xR, A_cL, A_cT, A_cR);
      ROW_MERGE(h_sA, c_sA, nhA, ncA, A_tgt, A_psk, actA);
      ROW_SHIFT(idxA, pidxA, lgtA, kA, actA);
      ROW_FMASC(A_xL, A_xT, A_xR, scA);

      // ---- row B: hoist -> merge -> shift -> FMA+sc (covers A's sc trip) --
      v2f B_xL[10], B_xT[10], B_xR[10];
      float B_cL, B_cT, B_cR;
      ROW_HOIST(h_sB, c_sB, nhB, ncB, B_iL, B_iR, B_psk,
                B_xL, B_xT, B_xR, B_cL, B_cT, B_cR);
      ROW_MERGE(h_sB, c_sB, nhB, ncB, B_tgt, B_psk, actB);
      ROW_SHIFT(idxB, pidxB, lgtB, kB2, actB);
      ROW_FMASC(B_xL, B_xT, B_xR, scB);

      // ---- nonlinearities (A's sc trip covered; B's covered by A's work) --
      ROW_NONLIN(scA, A_cL, A_cT, A_cR, nhA, ncA, A_pL, A_psk, kA, evA, lgtA);
      ROW_NONLIN(scB, B_cL, B_cT, B_cR, nhB, ncB, B_pL, B_psk, kB2, evB, lgtB);
    }

    // ---- gumbel transforms for row i+1 (off-chain) ----
    gA = -__logf(-__logf(u_cA + 1e-20f) + 1e-20f);
    gB = -__logf(-__logf(u_cB + 1e-20f) + 1e-20f);
    u_cA = u_dA;
    u_cB = u_dB;
  }

  const int rootA = rdl_i(idxA, 0);
  const int rootB = rdl_i(idxB, 0);
  if (lane < 20) {
    out[rowA * 20 + lane] = h_sA[rootA * 20 + lane];
    out[rowB * 20 + lane] = h_sB[rootB * 20 + lane];
  }
}

}  // namespace

extern "C" void kernel_launch(void* const* d_in, const int* in_sizes, int n_in,
                              void* d_out, int out_size, void* d_ws, size_t ws_size,
                              hipStream_t stream) {
  const float* input_h  = (const float*)d_in[0];
  const float* input_c  = (const float*)d_in[1];
  const float* W_reduce = (const float*)d_in[2];
  const float* b_reduce = (const float*)d_in[3];
  const float* W_comp   = (const float*)d_in[4];
  const float* b_comp   = (const float*)d_in[5];
  const float* query    = (const float*)d_in[6];
  const float* u_noise  = (const float*)d_in[7];
  const int*   length   = (const int*)d_in[8];
  float* out = (float*)d_out;

  float* H0 = (float*)d_ws;
  float* C0 = H0 + (size_t)kB * kL * kLow;

  reduce_kernel<<<dim3(2 * kB), dim3(256), 0, stream>>>(
      input_h, input_c, W_reduce, b_reduce, H0, C0);
  pyramid_kernel<<<dim3(kB / 2), dim3(64), 0, stream>>>(
      H0, C0, W_comp, b_comp, query, u_noise, length, out);
}

// Round 14
// 175.314 us; speedup vs baseline: 1.2326x; 1.2326x over previous
//
#include <hip/hip_runtime.h>
#include <cmath>
#include <cfloat>

namespace {

constexpr int kB   = 1024;
constexpr int kL   = 64;
constexpr int kHid = 512;
constexpr int kLow = 20;
constexpr int kLM1 = 63;              // L-1
constexpr int kRowElems = kL * kLow;  // 1280 floats per batch row of h0/c0

typedef float v2f __attribute__((ext_vector_type(2)));

__device__ __forceinline__ float fsig(float x) {
  return __builtin_amdgcn_rcpf(1.0f + __expf(-x));
}
__device__ __forceinline__ float ftanhf(float x) {
  return 1.0f - 2.0f * __builtin_amdgcn_rcpf(1.0f + __expf(2.0f * x));
}
__device__ __forceinline__ int rdl_i(int v, int l) {
  return __builtin_amdgcn_readlane(v, l);
}
__device__ __forceinline__ float rdl_f(float v, int l) {
  return __int_as_float(__builtin_amdgcn_readlane(__float_as_int(v), l));
}
// order-preserving float -> u32 sort key (key > 0 for all non-NaN floats)
__device__ __forceinline__ unsigned sortkey(float z) {
  const unsigned ub = __float_as_uint(z);
  return ((int)ub < 0) ? ~ub : (ub | 0x80000000u);
}

// DPP helpers (ctrl must be a literal -> macros).
#define DPPI(v, ctrl) __builtin_amdgcn_update_dpp((v), (v), (ctrl), 0xF, 0xF, false)
#define DPPF(v, ctrl) __int_as_float(DPPI(__float_as_int(v), (ctrl)))
#define DPPF0(v, ctrl)                                                        \
  __int_as_float(__builtin_amdgcn_update_dpp(0, __float_as_int(v), (ctrl),    \
                                             0xF, 0xF, true))
#define UMAX_STAGE(CTRL)                                                      \
  {                                                                           \
    const unsigned o_ = (unsigned)DPPI((int)m, CTRL);                         \
    m = (m > o_) ? m : o_;                                                    \
  }

// packed 2xf32 FMA
#define PKFMA(ACC, X, W)                                                      \
  asm("v_pk_fma_f32 %0, %1, %2, %0" : "+v"(ACC) : "v"(X), "v"(W))

// logit: sum over each 32-lane half; totals land in lanes 31 and 63.
#define LOGIT_REDUCE(PR_)                                                     \
  {                                                                           \
    PR_ += DPPF0(PR_, 0xB1);                                                  \
    PR_ += DPPF0(PR_, 0x4E);                                                  \
    PR_ += DPPF0(PR_, 0x141);                                                 \
    PR_ += DPPF0(PR_, 0x140);                                                 \
    PR_ += DPPF0(PR_, 0x142);                                                 \
  }

// ---------------------------------------------------------------------------
// Phase 1 (unchanged, known-best ~61 us timed): h0/c0 = X @ W_reduce + b
// ---------------------------------------------------------------------------
__global__ __launch_bounds__(256, 6)
void reduce_kernel(const float* __restrict__ Xh, const float* __restrict__ Xc,
                   const float* __restrict__ W, const float* __restrict__ bv,
                   float* __restrict__ H0, float* __restrict__ C0) {
  __shared__ float xs[5184];       // 64 rows x pitch 65; reused as scratch
  __shared__ float wsm[64 * 20];   // W chunk

  const int bid = blockIdx.x;
  const float* __restrict__ X = (bid < kB) ? Xh : Xc;
  float* __restrict__ O       = (bid < kB) ? H0 : C0;
  const int b = bid & (kB - 1);
  X += (size_t)b * kL * kHid;
  O += (size_t)b * kRowElems;

  const int tid  = threadIdx.x;
  const int wave = tid >> 6;
  const int lane = tid & 63;

  float acc[20];
#pragma unroll
  for (int d = 0; d < 20; ++d) acc[d] = 0.0f;

  for (int ch = 0; ch < 8; ++ch) {
    __syncthreads();
#pragma unroll
    for (int r = 0; r < 4; ++r) {
      int f   = r * 256 + tid;
      int row = f >> 4;
      int c4  = (f & 15) << 2;
      float4 v = *(const float4*)(X + row * kHid + ch * 64 + c4);
      *(float4*)(xs + row * 65 + c4) = v;
    }
#pragma unroll
    for (int r = 0; r < 5; ++r) {
      int f = r * 256 + tid;
      wsm[f] = W[ch * 1280 + f];
    }
    __syncthreads();
#pragma unroll
    for (int kk = 0; kk < 16; ++kk) {
      int k = wave * 16 + kk;
      float x = xs[lane * 65 + k];
      const float4* wp = (const float4*)(wsm + k * 20);
      float4 w0 = wp[0], w1 = wp[1], w2 = wp[2], w3 = wp[3], w4 = wp[4];
      acc[0]  = fmaf(x, w0.x, acc[0]);  acc[1]  = fmaf(x, w0.y, acc[1]);
      acc[2]  = fmaf(x, w0.z, acc[2]);  acc[3]  = fmaf(x, w0.w, acc[3]);
      acc[4]  = fmaf(x, w1.x, acc[4]);  acc[5]  = fmaf(x, w1.y, acc[5]);
      acc[6]  = fmaf(x, w1.z, acc[6]);  acc[7]  = fmaf(x, w1.w, acc[7]);
      acc[8]  = fmaf(x, w2.x, acc[8]);  acc[9]  = fmaf(x, w2.y, acc[9]);
      acc[10] = fmaf(x, w2.z, acc[10]); acc[11] = fmaf(x, w2.w, acc[11]);
      acc[12] = fmaf(x, w3.x, acc[12]); acc[13] = fmaf(x, w3.y, acc[13]);
      acc[14] = fmaf(x, w3.z, acc[14]); acc[15] = fmaf(x, w3.w, acc[15]);
      acc[16] = fmaf(x, w4.x, acc[16]); acc[17] = fmaf(x, w4.y, acc[17]);
      acc[18] = fmaf(x, w4.z, acc[18]); acc[19] = fmaf(x, w4.w, acc[19]);
    }
  }

  __syncthreads();
  float* red = xs;
#pragma unroll
  for (int d = 0; d < 20; ++d) red[wave * 1280 + lane * 20 + d] = acc[d];
  __syncthreads();
#pragma unroll
  for (int r = 0; r < 5; ++r) {
    int f = r * 256 + tid;
    float s = (red[f] + red[1280 + f]) + (red[2560 + f] + red[3840 + f]);
    O[f] = s + bv[f % 20];
  }
}

// LDS-weight TreeLSTM eval of one (pair, dim) unit — init pass only.
#define EVAL_UNIT(A_, B2_, PS_, DD_, HN_)                                     \
  {                                                                           \
    float ai = bcs[DD_], af = bcs[20 + DD_], ag = bcs[40 + DD_],              \
          au = bcs[60 + DD_], ao = bcs[80 + DD_];                             \
    const int xa_ = (A_)*20, xb_ = (B2_)*20, wr_ = (DD_)*44;                  \
    _Pragma("unroll")                                                         \
    for (int kq = 0; kq < 10; ++kq) {                                         \
      const float4 xq = (kq < 5)                                              \
          ? *(const float4*)(h_state + xa_ + kq * 4)                          \
          : *(const float4*)(h_state + xb_ + (kq - 5) * 4);                   \
      const float4 wi = *(const float4*)(Wt + wr_ + kq * 4);                  \
      const float4 wf = *(const float4*)(Wt + 880  + wr_ + kq * 4);           \
      const float4 wg = *(const float4*)(Wt + 1760 + wr_ + kq * 4);           \
      const float4 wu = *(const float4*)(Wt + 2640 + wr_ + kq * 4);           \
      const float4 wo = *(const float4*)(Wt + 3520 + wr_ + kq * 4);           \
      ai = fmaf(xq.x, wi.x, ai); ai = fmaf(xq.y, wi.y, ai);                   \
      ai = fmaf(xq.z, wi.z, ai); ai = fmaf(xq.w, wi.w, ai);                   \
      af = fmaf(xq.x, wf.x, af); af = fmaf(xq.y, wf.y, af);                   \
      af = fmaf(xq.z, wf.z, af); af = fmaf(xq.w, wf.w, af);                   \
      ag = fmaf(xq.x, wg.x, ag); ag = fmaf(xq.y, wg.y, ag);                   \
      ag = fmaf(xq.z, wg.z, ag); ag = fmaf(xq.w, wg.w, ag);                   \
      au = fmaf(xq.x, wu.x, au); au = fmaf(xq.y, wu.y, au);                   \
      au = fmaf(xq.z, wu.z, au); au = fmaf(xq.w, wu.w, au);                   \
      ao = fmaf(xq.x, wo.x, ao); ao = fmaf(xq.y, wo.y, ao);                   \
      ao = fmaf(xq.z, wo.z, ao); ao = fmaf(xq.w, wo.w, ao);                   \
    }                                                                         \
    const float cl_ = c_state[(A_)*20 + (DD_)],                               \
                cr_ = c_state[(B2_)*20 + (DD_)];                              \
    const float cn_ = cl_ * fsig(af + 1.0f) + cr_ * fsig(ag + 1.0f) +         \
                      ftanhf(au) * fsig(ai);                                  \
    (HN_) = fsig(ao) * ftanhf(cn_);                                           \
    nh[(PS_)*20 + (DD_)] = (HN_);                                             \
    nc[(PS_)*20 + (DD_)] = cn_;                                               \
  }

// ---------------------------------------------------------------------------
// Phase 2: per-row Gumbel tree pyramid, ONE WAVE per row.
// R14: argmax for iter i+1 runs EARLY (masked, excluding the two refreshed
// positions) right after the shift — its DPP chain fills the hoist/FMA stall
// windows. Final k(i+1) = 3-candidate fold in u32 key space (exact tie
// semantics: max value, ties -> lowest index).
// ---------------------------------------------------------------------------
__global__ __launch_bounds__(64, 1)
void pyramid_kernel(const float* __restrict__ H0, const float* __restrict__ C0,
                    const float* __restrict__ Wc, const float* __restrict__ bcg,
                    const float* __restrict__ query, const float* __restrict__ U,
                    const int* __restrict__ length, float* __restrict__ out) {
  __shared__ float h_state[64 * 20];
  __shared__ float c_state[64 * 20];
  __shared__ float nh[63 * 20];     // cached pair h_new, by pair SLOT
  __shared__ float nc[63 * 20];     // cached pair c_new
  __shared__ float Wt[100 * 44];    // transposed W_comp (init only)
  __shared__ float bcs[100];        // bias (init only)
  __shared__ float qvs[20];         // query (init only)
  __shared__ float sc[200];         // gate-sum scratch: [pair][100]

  const int b    = blockIdx.x;
  const int lane = threadIdx.x;     // one wave
  const int p    = lane >> 5;       // nonlin phase: pair select
  const int dd   = lane & 31;       // nonlin phase: output dim (<20 active)
  const int ddc  = dd < 20 ? dd : 19;
  int len = length[b];
  len = len < 1 ? 1 : (len > 64 ? 64 : len);

  // ---- stage ----
  {
    const float4* h4 = (const float4*)(H0 + (size_t)b * kRowElems);
    const float4* c4 = (const float4*)(C0 + (size_t)b * kRowElems);
#pragma unroll
    for (int r = 0; r < 5; ++r) {
      int f = r * 64 + lane;  // 320 float4 per array
      ((float4*)h_state)[f] = h4[f];
      ((float4*)c_state)[f] = c4[f];
    }
  }
  for (int f = lane; f < 4000; f += 64) {
    int c = f / 40, k = f - c * 40;
    Wt[c * 44 + k] = Wc[k * 100 + c];
  }
  for (int f = lane; f < 100; f += 64) bcs[f] = bcg[f];
  if (lane < 20) qvs[lane] = query[lane];

  // ---- loop weights: output-column split, straight from global ----
  const bool cact = lane < 50;
  const int  c0   = cact ? 2 * lane : 0;
  const int  c1   = c0 + 1;
  v2f Wv0[20], Wv1[20];   // [k2] = {W[2k2][c], W[2k2+1][c]}
#pragma unroll
  for (int k2 = 0; k2 < 20; ++k2) {
    Wv0[k2] = (v2f){Wc[(2 * k2) * 100 + c0], Wc[(2 * k2 + 1) * 100 + c0]};
    Wv1[k2] = (v2f){Wc[(2 * k2) * 100 + c1], Wc[(2 * k2 + 1) * 100 + c1]};
  }
  const float bb0 = bcg[c0], bb1 = bcg[c1];
  const float qv_r = query[ddc];

  // per-lane register bookkeeping (position-indexed)
  int   idx_r  = lane;
  int   pidx_r = lane;
  float lgt_r  = -FLT_MAX;

  const int col = lane < 62 ? lane : 62;
  const float u_row0 = U[b * kLM1 + col];
  float u_c = U[(size_t)1 * (kB * kLM1) + b * kLM1 + col];  // row 1

  // ---- init: evaluate all 63 adjacent pairs (LDS weights, parallel) ----
#pragma unroll 1
  for (int r = 0; r < 20; ++r) {
    int uu = r * 64 + lane;
    if (uu < 1260) {
      int pp = uu / 20, d2 = uu - pp * 20;
      float hn_;
      EVAL_UNIT(pp, pp + 1, pp, d2, hn_);
      (void)hn_;
    }
  }
  if (lane < 63) {
    float s = 0.0f;
#pragma unroll
    for (int q = 0; q < 5; ++q) {
      const float4 t  = *(const float4*)(nh  + lane * 20 + q * 4);
      const float4 qv = *(const float4*)(qvs + q * 4);
      s = fmaf(t.x, qv.x, s); s = fmaf(t.y, qv.y, s);
      s = fmaf(t.z, qv.z, s); s = fmaf(t.w, qv.w, s);
    }
    lgt_r = s;
  }

  // ---- pre-loop: full argmax for iteration 0 ----
  int kCur = 0;
  {
    const float g0 = -__logf(-__logf(u_row0 + 1e-20f) + 1e-20f);
    unsigned key = sortkey(lgt_r + g0);
    const bool valid = (lane <= 62) && ((1 + lane) < len);
    if (!valid) key = 0u;
    unsigned m = key;
    UMAX_STAGE(0xB1); UMAX_STAGE(0x4E); UMAX_STAGE(0x141);
    UMAX_STAGE(0x140); UMAX_STAGE(0x142); UMAX_STAGE(0x143);
    const unsigned gmax = (unsigned)rdl_i((int)m, 63);
    const unsigned long long bal = __ballot(valid && (key == gmax));
    kCur = bal ? (int)(__ffsll(bal) - 1) : 0;
  }

  const int nIter = len - 1;
#pragma unroll 1
  for (int i = 0; i < nIter; ++i) {
    const int n = kL - i;      // current sequence length
    const int k = kCur;        // this iteration's argmax (from prev iter)

    // ---- gumbel row i+1 (u_c loaded >=1 iteration ago; off-chain) ----
    const float gnx = -__logf(-__logf(u_c + 1e-20f) + 1e-20f);

    // ---- issue U load for row i+2 (2-deep pipeline) ----
    float u_d = 0.0f;
    if (i + 2 <= kLM1 - 1) u_d = U[(size_t)(i + 2) * (kB * kLM1) + b * kLM1 + col];

    // ---- pre-shift lookups via readlane ----
    const int km1 = (k >= 1) ? k - 1 : 0;
    const int kp2 = (k <= n - 3) ? k + 2 : 0;
    const int tgt = rdl_i(idx_r,  k);
    const int psk = rdl_i(pidx_r, k);
    const int iA  = rdl_i(idx_r,  km1);
    const int pA  = rdl_i(pidx_r, km1);
    const int iB  = rdl_i(idx_r,  kp2);

    // ---- HOISTED eval reads (latency overlaps the VALU work below) ----
    v2f hA2[10], hT2[10], hB2[10];
#pragma unroll
    for (int q = 0; q < 5; ++q) {
      const float4 tA = *(const float4*)(h_state + iA * 20 + q * 4);
      const float4 tT = *(const float4*)(nh + psk * 20 + q * 4);
      const float4 tB = *(const float4*)(h_state + iB * 20 + q * 4);
      hA2[2*q]   = (v2f){tA.x, tA.y};  hA2[2*q+1] = (v2f){tA.z, tA.w};
      hT2[2*q]   = (v2f){tT.x, tT.y};  hT2[2*q+1] = (v2f){tT.z, tT.w};
      hB2[2*q]   = (v2f){tB.x, tB.y};  hB2[2*q+1] = (v2f){tB.z, tB.w};
    }
    const float cA_ = c_state[iA * 20 + ddc];   // pair A left c
    const float cT_ = nc[psk * 20 + ddc];       // merged node c
    const float cB_ = c_state[iB * 20 + ddc];   // pair B right c

    // ---- merge: winner's cached (h,c) -> state slot tgt (off-chain) ----
    if (lane < 20) {
      h_state[tgt * 20 + lane] = nh[psk * 20 + lane];
      c_state[tgt * 20 + lane] = nc[psk * 20 + lane];
    }

    // ---- shift position-indexed registers via DPP row_shl:1 ----
    {
      int   sI = DPPI(idx_r,  0x101);
      int   sP = DPPI(pidx_r, 0x101);
      float sL = DPPF(lgt_r,  0x101);
      const int   bi16 = rdl_i(idx_r, 16),  bi32 = rdl_i(idx_r, 32),
                  bi48 = rdl_i(idx_r, 48);
      const int   bp16 = rdl_i(pidx_r, 16), bp32 = rdl_i(pidx_r, 32),
                  bp48 = rdl_i(pidx_r, 48);
      const float bl16 = rdl_f(lgt_r, 16),  bl32 = rdl_f(lgt_r, 32),
                  bl48 = rdl_f(lgt_r, 48);
      if (lane == 15) { sI = bi16; sP = bp16; sL = bl16; }
      if (lane == 31) { sI = bi32; sP = bp32; sL = bl32; }
      if (lane == 47) { sI = bi48; sP = bp48; sL = bl48; }
      const bool doI = (lane >= k + 1) && (lane <= n - 2);
      const bool doP = (lane >= k + 1) && (lane <= n - 3);
      if (doI) idx_r = sI;
      if (doP) { pidx_r = sP; lgt_r = sL; }
    }

    // ---- EARLY MASKED ARGMAX for iter i+1 (register-only; independent of
    //      the FMA/sc/nonlin below -> schedules into their stall windows).
    //      Excludes lanes k-1 and k (their lgt is refreshed by the eval). ----
    unsigned keyM;
    int jM;
    bool hasM;
    {
      const int n2 = n - 1;  // next iteration's sequence length
      unsigned key = sortkey(lgt_r + gnx);
      const bool validM = (lane <= n2 - 2) && ((i + 2 + lane) < len) &&
                          (lane != k - 1) && (lane != k);
      if (!validM) key = 0u;
      unsigned m = key;
      UMAX_STAGE(0xB1); UMAX_STAGE(0x4E); UMAX_STAGE(0x141);
      UMAX_STAGE(0x140); UMAX_STAGE(0x142); UMAX_STAGE(0x143);
      keyM = (unsigned)rdl_i((int)m, 63);
      const unsigned long long bal = __ballot(validM && (key == keyM));
      hasM = bal != 0;
      jM   = hasM ? (int)(__ffsll(bal) - 1) : 64;
    }

    // ---- evaluate both candidate pairs: column-split full-K dots ----
    if (i < len - 2) {
      const bool hasA = (k >= 1);
      const bool hasB = (k <= n - 3);

      v2f aA0 = (v2f){0.f, 0.f}, aA1 = aA0, aB0 = aA0, aB1 = aA0;
#pragma unroll
      for (int k2 = 0; k2 < 10; ++k2) {
        PKFMA(aA0, hA2[k2], Wv0[k2]);
        PKFMA(aA1, hA2[k2], Wv1[k2]);
        PKFMA(aB0, hT2[k2], Wv0[k2]);
        PKFMA(aB1, hT2[k2], Wv1[k2]);
      }
#pragma unroll
      for (int k2 = 10; k2 < 20; ++k2) {
        PKFMA(aA0, hT2[k2 - 10], Wv0[k2]);
        PKFMA(aA1, hT2[k2 - 10], Wv1[k2]);
        PKFMA(aB0, hB2[k2 - 10], Wv0[k2]);
        PKFMA(aB1, hB2[k2 - 10], Wv1[k2]);
      }

      if (cact) {
        *(v2f*)(sc + c0)       = (v2f){aA0[0] + aA0[1] + bb0,
                                       aA1[0] + aA1[1] + bb1};
        *(v2f*)(sc + 100 + c0) = (v2f){aB0[0] + aB0[1] + bb0,
                                       aB1[0] + aB1[1] + bb1};
      }

      const float* scp = sc + p * 100;
      const float i_ = scp[ddc],      fl_ = scp[20 + ddc],
                  fr_ = scp[40 + ddc], u_ = scp[60 + ddc],
                  o_ = scp[80 + ddc];
      const float cl_ = (p == 0) ? cA_ : cT_;
      const float cr_ = (p == 0) ? cT_ : cB_;
      const float cn_ = cl_ * fsig(fl_ + 1.0f) + cr_ * fsig(fr_ + 1.0f) +
                        ftanhf(u_) * fsig(i_);
      const float hn_ = fsig(o_) * ftanhf(cn_);
      const int   slot = (p == 0) ? pA : psk;
      const bool  mine = (p == 0) ? hasA : hasB;
      if (mine && dd < 20) {
        nh[slot * 20 + dd] = hn_;
        nc[slot * 20 + dd] = cn_;
      }
      float pr = (dd < 20) ? hn_ * qv_r : 0.0f;
      LOGIT_REDUCE(pr);
      const float vA = rdl_f(pr, 31);
      const float vB = rdl_f(pr, 63);
      if (hasA && lane == k - 1) lgt_r = vA;
      if (hasB && lane == k)     lgt_r = vB;

      // ---- fold {A, B, maskedMax} in key space -> k for iter i+1.
      //      Exact semantics: max value, ties -> lowest index. ----
      const int n2 = n - 1;
      const bool vA_ok = hasA && ((i + 2 + (k - 1)) < len);  // k-1 <= n2-2 always
      const bool vB_ok = hasB && (k <= n2 - 2) && ((i + 2 + k) < len);
      const unsigned keyA = sortkey(vA + rdl_f(gnx, km1));
      const unsigned keyB = sortkey(vB + rdl_f(gnx, k));
      unsigned bk = 0u;
      int bj = 64;
      if (vA_ok) { bk = keyA; bj = k - 1; }
      if (vB_ok && (keyB > bk || (keyB == bk && k < bj))) { bk = keyB; bj = k; }
      if (hasM  && (keyM > bk || (keyM == bk && jM < bj))) { bk = keyM; bj = jM; }
      kCur = (bj < 64) ? bj : 0;
    }
    // (when i >= len-2 this was the last iteration; kCur unused)

    u_c = u_d;
  }

  const int root = rdl_i(idx_r, 0);
  if (lane < 20) {
    out[b * 20 + lane] = h_state[root * 20 + lane];
  }
}

}  // namespace

extern "C" void kernel_launch(void* const* d_in, const int* in_sizes, int n_in,
                              void* d_out, int out_size, void* d_ws, size_t ws_size,
                              hipStream_t stream) {
  const float* input_h  = (const float*)d_in[0];
  const float* input_c  = (const float*)d_in[1];
  const float* W_reduce = (const float*)d_in[2];
  const float* b_reduce = (const float*)d_in[3];
  const float* W_comp   = (const float*)d_in[4];
  const float* b_comp   = (const float*)d_in[5];
  const float* query    = (const float*)d_in[6];
  const float* u_noise  = (const float*)d_in[7];
  const int*   length   = (const int*)d_in[8];
  float* out = (float*)d_out;

  float* H0 = (float*)d_ws;
  float* C0 = H0 + (size_t)kB * kL * kLow;

  reduce_kernel<<<dim3(2 * kB), dim3(256), 0, stream>>>(
      input_h, input_c, W_reduce, b_reduce, H0, C0);
  pyramid_kernel<<<dim3(kB), dim3(64), 0, stream>>>(
      H0, C0, W_comp, b_comp, query, u_noise, length, out);
}